// Round 3
// baseline (58.216 us; speedup 1.0000x reference)
//
#include <hip/hip_runtime.h>

#define SDIM 64
#define DDIM 128
#define HDIM 512

typedef __attribute__((ext_vector_type(8))) __bf16 bf16x8;
typedef __attribute__((ext_vector_type(4))) float f32x4;
typedef __attribute__((ext_vector_type(4))) float float4v;
typedef __attribute__((ext_vector_type(4))) unsigned int u32x4;

__device__ __forceinline__ unsigned short f2bfc(float f) {
    __bf16 h = (__bf16)f;                      // RNE; compiler emits v_cvt(_pk)_bf16_f32
    return __builtin_bit_cast(unsigned short, h);
}
__device__ __forceinline__ float bf2f(unsigned short b) {
    union { unsigned int u; float f; } v; v.u = ((unsigned int)b) << 16;
    return v.f;
}

// swizzle on ushort index: XOR bits 3..5 with (row&7)  == byte ^= (row&7)<<4
#define SWZ(idx, row) ((idx) ^ (((row) & 7) << 3))

// ---------------------------------------------------------------------------
// Prep: transpose + fp32->bf16 convert the 4 weight matrices into ws.
// ws layout (ushort units): Wt1[512][128] @0, Wt2[128][512] @65536,
//                           Wt3[512][256] @131072, Wt4[128][512] @262144
// ---------------------------------------------------------------------------
__global__ __launch_bounds__(256) void kprep(
    const float* __restrict__ W1, const float* __restrict__ W2,
    const float* __restrict__ W3, const float* __restrict__ W4,
    unsigned short* __restrict__ ws) {
    __shared__ unsigned short tile[32][33];
    int b = blockIdx.x;
    const float* src; unsigned short* dst; int K, N, tr, tc;
    if (b < 64)        { src = W1; dst = ws;          K = 128; N = 512; int t = b;       tr = t >> 4; tc = t & 15; }
    else if (b < 128)  { src = W2; dst = ws + 65536;  K = 512; N = 128; int t = b - 64;  tr = t >> 2; tc = t & 3;  }
    else if (b < 256)  { src = W3; dst = ws + 131072; K = 256; N = 512; int t = b - 128; tr = t >> 4; tc = t & 15; }
    else               { src = W4; dst = ws + 262144; K = 512; N = 128; int t = b - 256; tr = t >> 2; tc = t & 3;  }
    int tid = threadIdx.x;
#pragma unroll
    for (int i = 0; i < 4; i++) {
        int e = tid + i * 256;
        int r = e >> 5, c = e & 31;
        tile[r][c] = f2bfc(src[(tr * 32 + r) * N + tc * 32 + c]);
    }
    __syncthreads();
#pragma unroll
    for (int i = 0; i < 4; i++) {
        int e = tid + i * 256;
        int r = e >> 5, c = e & 31;      // r: n-in-tile, c: k-in-tile
        dst[(tc * 32 + r) * K + tr * 32 + c] = tile[c][r];
    }
}

// ---------------------------------------------------------------------------
// Fused DeepSets block: grid 512 = (l, half). Each block: 32 rows of one l.
// 512 threads = 8 waves. LDS 56 KB -> 2 blocks/CU, 16 waves/CU.
// ---------------------------------------------------------------------------
__global__ __launch_bounds__(512, 4) void kmain(
    const float* __restrict__ x,
    const float* __restrict__ b1, const float* __restrict__ b2,
    const float* __restrict__ b3, const float* __restrict__ b4,
    const unsigned short* __restrict__ ws, float* __restrict__ out) {

    __shared__ __align__(16) unsigned short xs[SDIM * DDIM];   // 16 KB: all 64 rows of l (bf16)
    __shared__ __align__(16) unsigned short cc[32 * DDIM];     //  8 KB: cs, later cm (aliased)
    __shared__ __align__(16) unsigned short h1[32 * HDIM];     // 32 KB: hidden (also max-scratch overlay)

    const unsigned short* Wt1 = ws;
    const unsigned short* Wt2 = ws + 65536;
    const unsigned short* Wt3 = ws + 131072;
    const unsigned short* Wt4 = ws + 262144;

    const int tid  = threadIdx.x;
    const int lane = tid & 63;
    const int wid  = tid >> 6;            // 0..7
    const int bx   = blockIdx.x;
    const int l    = bx >> 1;
    const int hf   = bx & 1;              // which 32-row half of this l
    const int lr   = lane & 15;           // frag row (A) / col (B,C/D)
    const int lk   = (lane >> 4) << 3;    // frag k-offset {0,8,16,24}
    const int lq   = (lane >> 4) << 2;    // C/D row group {0,4,8,12}
    const float* xg = x + l * SDIM * DDIM;            // 64 rows of this l

    // max-phase scratch overlaid on h1 (h1 first written in GEMM1 epilogue)
    float* pm1 = (float*)h1;              // [4][128] partial max1
    float* pm2 = pm1 + 512;               // [4][128] partial max2
    int*   pi1 = (int*)(pm2 + 512);       // [4][128] partial argmax
    float* fm1 = (float*)(pi1 + 512);     // [128]
    float* fm2 = fm1 + 128;               // [128]
    int*   fi  = (int*)(fm2 + 128);       // [128]

    // ---- stage all 64 rows of x -> xs (bf16, swizzled), 16B chunks ----
#pragma unroll
    for (int it = 0; it < 2; it++) {
        int ch   = tid + it * 512;        // chunk of 8 elements
        int base = ch * 8;
        int row  = base >> 7;
        float4v v0 = *(const float4v*)(xg + base);
        float4v v1 = *(const float4v*)(xg + base + 4);
        u32x4 p;
        p.x = (unsigned int)f2bfc(v0.x) | ((unsigned int)f2bfc(v0.y) << 16);
        p.y = (unsigned int)f2bfc(v0.z) | ((unsigned int)f2bfc(v0.w) << 16);
        p.z = (unsigned int)f2bfc(v1.x) | ((unsigned int)f2bfc(v1.y) << 16);
        p.w = (unsigned int)f2bfc(v1.z) | ((unsigned int)f2bfc(v1.w) << 16);
        *(u32x4*)(&xs[SWZ(base, row)]) = p;
    }
    __syncthreads();

    // ---- masked all-pairs max via top-2, parallel over 512 threads ----
    {   // quarter q scans 16 rows of column d
        int d = tid & 127, q = tid >> 7;
        float m1 = -3.4e38f, m2 = -3.4e38f; int i1 = -1;
#pragma unroll
        for (int i = 0; i < 16; i++) {
            int row = q * 16 + i;
            float v = bf2f(xs[SWZ(row * DDIM + d, row)]);
            if (v > m1) { m2 = m1; m1 = v; i1 = row; }
            else if (v > m2) { m2 = v; }
        }
        pm1[q * 128 + d] = m1; pm2[q * 128 + d] = m2; pi1[q * 128 + d] = i1;
    }
    __syncthreads();
    if (tid < 128) {
        int d = tid;
        float m1 = pm1[d], m2 = pm2[d]; int i1 = pi1[d];
#pragma unroll
        for (int q = 1; q < 4; q++) {
            float a1 = pm1[q * 128 + d], a2 = pm2[q * 128 + d]; int ai = pi1[q * 128 + d];
            if (a1 > m1) { m2 = fmaxf(m1, a2); m1 = a1; i1 = ai; }
            else         { m2 = fmaxf(m2, a1); }
        }
        fm1[d] = m1; fm2[d] = m2; fi[d] = i1;
    }
    __syncthreads();
    {   // write cs (own 32 rows): cs[j][d] = max(0, j==argmax ? m2 : m1)
        int jl = tid >> 4;                 // 0..31 local row
        int d0 = (tid & 15) * 8;
        int jg = hf * 32 + jl;             // global row in l
        unsigned short t8[8];
#pragma unroll
        for (int e = 0; e < 8; e++) {
            int d = d0 + e;
            float v = (jg == fi[d]) ? fm2[d] : fm1[d];
            t8[e] = f2bfc(fmaxf(v, 0.0f));
        }
        u32x4 p;
        p.x = (unsigned int)t8[0] | ((unsigned int)t8[1] << 16);
        p.y = (unsigned int)t8[2] | ((unsigned int)t8[3] << 16);
        p.z = (unsigned int)t8[4] | ((unsigned int)t8[5] << 16);
        p.w = (unsigned int)t8[6] | ((unsigned int)t8[7] << 16);
        *(u32x4*)(&cc[SWZ(jl * DDIM + d0, jl)]) = p;
    }
    __syncthreads();

    // ---- GEMM1: h1 = relu(cc[32x128] @ W1 + b1); wave -> 64 cols ----
    {
        f32x4 acc[2][4];
#pragma unroll
        for (int m = 0; m < 2; m++)
#pragma unroll
            for (int n = 0; n < 4; n++) acc[m][n] = (f32x4)0.0f;
#pragma unroll
        for (int ks = 0; ks < 4; ks++) {
            bf16x8 a[2];
#pragma unroll
            for (int m = 0; m < 2; m++) {
                int row = m * 16 + lr;
                a[m] = *(const bf16x8*)(&cc[SWZ(row * DDIM + ks * 32 + lk, row)]);
            }
#pragma unroll
            for (int n = 0; n < 4; n++) {
                int ncol = wid * 64 + n * 16 + lr;
                bf16x8 bfr = *(const bf16x8*)(&Wt1[ncol * 128 + ks * 32 + lk]);
#pragma unroll
                for (int m = 0; m < 2; m++)
                    acc[m][n] = __builtin_amdgcn_mfma_f32_16x16x32_bf16(a[m], bfr, acc[m][n], 0, 0, 0);
            }
        }
#pragma unroll
        for (int n = 0; n < 4; n++) {
            int col = wid * 64 + n * 16 + lr;
            float bias = b1[col];
#pragma unroll
            for (int m = 0; m < 2; m++)
#pragma unroll
                for (int r = 0; r < 4; r++) {
                    int row = m * 16 + lq + r;
                    h1[SWZ(row * HDIM + col, row)] = f2bfc(fmaxf(acc[m][n][r] + bias, 0.0f));
                }
        }
    }
    __syncthreads();

    // ---- GEMM2: cm = h1[32x512] @ W2 + b2; wave -> 16 cols ----
    {
        f32x4 acc[2];
        acc[0] = (f32x4)0.0f; acc[1] = (f32x4)0.0f;
        const int ncol = wid * 16 + lr;
#pragma unroll
        for (int ks = 0; ks < 16; ks++) {
            bf16x8 bfr = *(const bf16x8*)(&Wt2[ncol * 512 + ks * 32 + lk]);
#pragma unroll
            for (int m = 0; m < 2; m++) {
                int row = m * 16 + lr;
                bf16x8 a = *(const bf16x8*)(&h1[SWZ(row * HDIM + ks * 32 + lk, row)]);
                acc[m] = __builtin_amdgcn_mfma_f32_16x16x32_bf16(a, bfr, acc[m], 0, 0, 0);
            }
        }
        float bias = b2[ncol];
#pragma unroll
        for (int m = 0; m < 2; m++)
#pragma unroll
            for (int r = 0; r < 4; r++) {
                int row = m * 16 + lq + r;
                cc[SWZ(row * DDIM + ncol, row)] = f2bfc(acc[m][r] + bias);
            }
    }
    __syncthreads();

    // ---- GEMM3: h1 = relu([xs_ownrows | cm][32x256] @ W3 + b3) ----
    {
        f32x4 acc[2][4];
#pragma unroll
        for (int m = 0; m < 2; m++)
#pragma unroll
            for (int n = 0; n < 4; n++) acc[m][n] = (f32x4)0.0f;
#pragma unroll
        for (int ks = 0; ks < 8; ks++) {
            bf16x8 a[2];
#pragma unroll
            for (int m = 0; m < 2; m++) {
                int row = m * 16 + lr;
                if (ks < 4) {
                    int gr = hf * 32 + row;      // xs holds all 64 rows
                    a[m] = *(const bf16x8*)(&xs[SWZ(gr * DDIM + ks * 32 + lk, gr)]);
                } else {
                    a[m] = *(const bf16x8*)(&cc[SWZ(row * DDIM + (ks - 4) * 32 + lk, row)]);
                }
            }
#pragma unroll
            for (int n = 0; n < 4; n++) {
                int ncol = wid * 64 + n * 16 + lr;
                bf16x8 bfr = *(const bf16x8*)(&Wt3[ncol * 256 + ks * 32 + lk]);
#pragma unroll
                for (int m = 0; m < 2; m++)
                    acc[m][n] = __builtin_amdgcn_mfma_f32_16x16x32_bf16(a[m], bfr, acc[m][n], 0, 0, 0);
            }
        }
#pragma unroll
        for (int n = 0; n < 4; n++) {
            int col = wid * 64 + n * 16 + lr;
            float bias = b3[col];
#pragma unroll
            for (int m = 0; m < 2; m++)
#pragma unroll
                for (int r = 0; r < 4; r++) {
                    int row = m * 16 + lq + r;
                    h1[SWZ(row * HDIM + col, row)] = f2bfc(fmaxf(acc[m][n][r] + bias, 0.0f));
                }
        }
    }
    __syncthreads();

    // ---- GEMM4 + residual: out = x + (h1[32x512] @ W4 + b4), fp32 ----
    {
        f32x4 acc[2];
        acc[0] = (f32x4)0.0f; acc[1] = (f32x4)0.0f;
        const int ncol = wid * 16 + lr;
#pragma unroll
        for (int ks = 0; ks < 16; ks++) {
            bf16x8 bfr = *(const bf16x8*)(&Wt4[ncol * 512 + ks * 32 + lk]);
#pragma unroll
            for (int m = 0; m < 2; m++) {
                int row = m * 16 + lr;
                bf16x8 a = *(const bf16x8*)(&h1[SWZ(row * HDIM + ks * 32 + lk, row)]);
                acc[m] = __builtin_amdgcn_mfma_f32_16x16x32_bf16(a, bfr, acc[m], 0, 0, 0);
            }
        }
        float bias = b4[ncol];
#pragma unroll
        for (int m = 0; m < 2; m++)
#pragma unroll
            for (int r = 0; r < 4; r++) {
                int row = m * 16 + lq + r;           // local row 0..31
                int gr  = hf * 32 + row;             // row within l
                float v = acc[m][r] + bias + xg[gr * DDIM + ncol];
                out[(l * SDIM + gr) * DDIM + ncol] = v;
            }
    }
}

extern "C" void kernel_launch(void* const* d_in, const int* in_sizes, int n_in,
                              void* d_out, int out_size, void* d_ws, size_t ws_size,
                              hipStream_t stream) {
    const float* x  = (const float*)d_in[0];
    const float* W1 = (const float*)d_in[1];
    const float* b1 = (const float*)d_in[2];
    const float* W2 = (const float*)d_in[3];
    const float* b2 = (const float*)d_in[4];
    const float* W3 = (const float*)d_in[5];
    const float* b3 = (const float*)d_in[6];
    const float* W4 = (const float*)d_in[7];
    const float* b4 = (const float*)d_in[8];
    unsigned short* ws = (unsigned short*)d_ws;
    float* out = (float*)d_out;

    kprep<<<320, 256, 0, stream>>>(W1, W2, W3, W4, ws);
    kmain<<<512, 512, 0, stream>>>(x, b1, b2, b3, b4, ws, out);
}